// Round 10
// baseline (1209.882 us; speedup 1.0000x reference)
//
#include <hip/hip_runtime.h>
#include <hip/hip_bf16.h>
#include <stdint.h>

typedef float f32x4 __attribute__((ext_vector_type(4)));
typedef int i32x4 __attribute__((ext_vector_type(4)));

// ---------------- async global -> LDS (16B/lane, wave-uniform LDS base) ----------------
__device__ __forceinline__ void gload_lds16(const signed char* g, signed char* l) {
    __builtin_amdgcn_global_load_lds(
        (const __attribute__((address_space(1))) unsigned int*)g,
        (__attribute__((address_space(3))) unsigned int*)l,
        16, 0, 0);
}

// ---------------- per-row activation quantization: f32 -> i8, qrow = amax/127 ----------------
__global__ __launch_bounds__(256) void quant_rows_kernel(
        const float* __restrict__ A, signed char* __restrict__ Aq,
        float* __restrict__ qrow, int K) {
    const long row = blockIdx.x;
    const float* a = A + row * (long)K;
    signed char* o = Aq + row * (long)K;
    const int tid = threadIdx.x;
    const int nch = K >> 2;                       // f32x4 chunks per row
    float amax = 0.f;
    for (int c = tid; c < nch; c += 256) {
        f32x4 v = ((const f32x4*)a)[c];
        amax = fmaxf(amax, fmaxf(fmaxf(fabsf(v[0]), fabsf(v[1])),
                                 fmaxf(fabsf(v[2]), fabsf(v[3]))));
    }
#pragma unroll
    for (int off = 32; off; off >>= 1)
        amax = fmaxf(amax, __shfl_xor(amax, off, 64));
    __shared__ float red[4];
    if ((tid & 63) == 0) red[tid >> 6] = amax;
    __syncthreads();
    amax = fmaxf(fmaxf(red[0], red[1]), fmaxf(red[2], red[3]));
    const float s = amax > 0.f ? 127.f / amax : 0.f;
    if (tid == 0) qrow[row] = amax > 0.f ? amax / 127.f : 0.f;
    for (int c = tid; c < nch; c += 256) {       // second sweep: row is L1/L2-hot
        f32x4 v = ((const f32x4*)a)[c];
        int r = 0;
#pragma unroll
        for (int i = 0; i < 4; ++i) {
            int q = (int)__builtin_rintf(v[i] * s);
            r |= (q & 0xff) << (8 * i);
        }
        ((int*)o)[c] = r;
    }
}

// ---------------- weight conversion: i32 (int8-range) -> i8, exact ----------------
__global__ __launch_bounds__(256) void cvt_i32_i8_kernel(
        const int* __restrict__ in, signed char* __restrict__ out, long n) {
    long base = ((long)blockIdx.x * 256 + threadIdx.x) * 16;
    long stride = (long)gridDim.x * 256 * 16;
    for (long i = base; i < n; i += stride) {
        i32x4 pk;
#pragma unroll
        for (int c = 0; c < 4; ++c) {
            i32x4 v = *(const i32x4*)(in + i + c * 4);
            pk[c] = (v[0] & 0xff) | ((v[1] & 0xff) << 8) |
                    ((v[2] & 0xff) << 16) | ((v[3] & 0xff) << 24);
        }
        *(i32x4*)(out + i) = pk;
    }
}

// =====================================================================
// 128x256 i8 GEMM, BK=64, A global->reg (JIT), B-only LDS double-buffer.
// 512 thr = 8 waves (2M x 4N), wave tile 64x64, acc = 16 i32x4 = 64 VGPR.
// Target: <=128 VGPR -> 4 waves/SIMD -> 2 blocks/CU (cross-block overlap).
// LDS 32 KiB: buf*16384 + j*8192, B region = 256 rows x 64 cols i8,
// 64-B rows; swizzle: LDS[row][slot16B] holds global slot ^ ((row>>1)&3).
// Per phase (K-tile t): {BAR; stage B(t+1); load A(t)->reg; vm(6)[B(t) landed];
//  BAR; read B frags; vm(2)[A(t) landed]; 16 MFMA}.  vmcnt ledger:
// entering = 2 (st(t)); +2 st(t+1) +4 A(t) = 8 -> vm(6) drains st(t);
// vm(2) drains A(t) leaving st(t+1).  Final phase: vm(4)/vm(0).
// =====================================================================

#define PHASE(T, BUF, DOSTAGE, VMST, VMA)                                    \
  {                                                                          \
    __builtin_amdgcn_s_barrier();                                            \
    __builtin_amdgcn_sched_barrier(0);                                       \
    if (DOSTAGE) {                                                           \
      gload_lds16(W + wOff0 + ((T) + 1) * 64,                                \
                  smem + (1 - (BUF)) * 16384 + ldsSt);                       \
      gload_lds16(W + wOff1 + ((T) + 1) * 64,                                \
                  smem + (1 - (BUF)) * 16384 + 8192 + ldsSt);                \
    }                                                                        \
    _Pragma("unroll")                                                        \
    for (int ml = 0; ml < 4; ++ml)                                           \
      fa[ml] = *(const i32x4*)(A + aAddr[ml] + (T) * 64);                    \
    asm volatile("s_waitcnt vmcnt(" #VMST ")" ::: "memory");                 \
    __builtin_amdgcn_s_barrier();                                            \
    __builtin_amdgcn_sched_barrier(0);                                       \
    _Pragma("unroll")                                                        \
    for (int nl = 0; nl < 4; ++nl)                                           \
      fb[nl] = *(const i32x4*)(smem + (BUF) * 16384 + bRd[nl]);              \
    asm volatile("s_waitcnt vmcnt(" #VMA ")" ::: "memory");                  \
    __builtin_amdgcn_s_setprio(1);                                           \
    _Pragma("unroll")                                                        \
    for (int ml = 0; ml < 4; ++ml)                                           \
      _Pragma("unroll")                                                      \
      for (int nl = 0; nl < 4; ++nl)                                         \
        acc[ml][nl] = __builtin_amdgcn_mfma_i32_16x16x64_i8(                 \
            fa[ml], fb[nl], acc[ml][nl], 0, 0, 0);                           \
    __builtin_amdgcn_s_setprio(0);                                           \
  }

__global__ __launch_bounds__(512, 2) void gemm_i8_areg(
        const signed char* __restrict__ A,      // [M][K] i8
        const signed char* __restrict__ W,      // [N][K] i8
        const float* __restrict__ qrow,         // [M] row dequant scale
        const float* __restrict__ scales,       // [N]
        const float* __restrict__ bias,         // [N]
        float* __restrict__ C,                  // [M][N]
        int M, int N, int K) {
    extern __shared__ signed char smem[];       // 32768 B

    const int tid  = threadIdx.x;
    const int lane = tid & 63;
    const int wid  = tid >> 6;
    const int wr = wid >> 2;     // 0..1 : M half (64 rows each)
    const int wc = wid & 3;      // 0..3 : N quarter (64 cols each)
    const int fr = lane & 15;
    const int kg = lane >> 4;    // k-group / C-row-group

    const int nwg = gridDim.x;
    const int bid = blockIdx.x;
    const int swz = ((nwg & 7) == 0) ? ((bid & 7) * (nwg >> 3) + (bid >> 3)) : bid;
    const int tiles_n = N >> 8;                 // N / 256
    const int tm = swz / tiles_n;
    const int tn = swz % tiles_n;
    const int arow = tm << 7;                   // tile M = 128
    const int brow = tn << 8;                   // tile N = 256

    // ---- A global byte-offsets (thread-constant): row = arow+wr*64+ml*16+fr
    int aAddr[4];
#pragma unroll
    for (int ml = 0; ml < 4; ++ml)
        aAddr[ml] = (arow + wr * 64 + ml * 16 + fr) * K + kg * 16;

    // ---- B stage offsets: 2 issues x (512 lanes x 16B) = 16 KB (256 rows x 64B)
    const int srow = tid >> 2;                  // 0..127
    const int sswz = ((tid & 3) ^ ((srow >> 1) & 3)) << 4;   // pre-swizzled source
    const int wOff0 = (brow + srow) * K + sswz;
    const int wOff1 = (brow + 128 + srow) * K + sswz;
    const int ldsSt = wid * 1024;

    // ---- B LDS read byte-offsets: lrow = wc*64 + nl*16 + fr
    int bRd[4];
#pragma unroll
    for (int nl = 0; nl < 4; ++nl) {
        const int lrow = wc * 64 + nl * 16 + fr;
        bRd[nl] = lrow * 64 + ((kg ^ ((lrow >> 1) & 3)) << 4);
    }

    i32x4 acc[4][4] = {};
    i32x4 fa[4], fb[4];

    const int NT = K >> 6;       // K-tiles of 64; NT even, >= 2

    // ---- prologue: stage B tile 0 into buf0 (outstanding = 2)
    gload_lds16(W + wOff0, smem + ldsSt);
    gload_lds16(W + wOff1, smem + 8192 + ldsSt);

    // ---- main loop (pair-unrolled; each phase stages t+1)
    for (int i = 0; i < (NT >> 1) - 1; ++i) {
        const int t0 = 2 * i;
        PHASE(t0,     0, true, 6, 2);
        PHASE(t0 + 1, 1, true, 6, 2);
    }
    PHASE(NT - 2, 0, true,  6, 2);   // stages tile NT-1 into buf1
    PHASE(NT - 1, 1, false, 4, 0);   // no stage; drain all

    // ---- dequant row scales for this thread's 16 output rows
    float qr[4][4];
#pragma unroll
    for (int ml = 0; ml < 4; ++ml) {
        const int row0 = arow + wr * 64 + ml * 16 + kg * 4;
#pragma unroll
        for (int j = 0; j < 4; ++j)
            qr[ml][j] = qrow[row0 + j];
    }

    // ---- C write: out = acc * qrow[row] * scales[col] + bias[col]
    // 16x16 C/D layout: col = lane&15, row = (lane>>4)*4 + reg
#pragma unroll
    for (int nl = 0; nl < 4; ++nl) {
        const int col = tn * 256 + wc * 64 + nl * 16 + fr;
        const float s = scales[col];
        const float bb = bias[col];
#pragma unroll
        for (int ml = 0; ml < 4; ++ml) {
            const int row0 = arow + wr * 64 + ml * 16 + kg * 4;
#pragma unroll
            for (int j = 0; j < 4; ++j)
                C[(long)(row0 + j) * N + col] =
                    (float)acc[ml][nl][j] * (qr[ml][j] * s) + bb;
        }
    }
}

// ---------------- fallback: plain fp32 (odd shapes / tiny ws only) ----------------
__global__ __launch_bounds__(256) void gemm_fallback_kernel(
        const float* __restrict__ A, const int* __restrict__ W,
        const float* __restrict__ scales, const float* __restrict__ bias,
        float* __restrict__ C, int M, int N, int K) {
    __shared__ float As[64][16];
    __shared__ float Ws[64][16];
    const int tiles_n = N / 64;
    const int tm = blockIdx.x / tiles_n, tn = blockIdx.x % tiles_n;
    const int tid = threadIdx.x, tx = tid & 15, ty = tid >> 4;
    float acc[4][4] = {};
    for (int k0 = 0; k0 < K; k0 += 16) {
        __syncthreads();
#pragma unroll
        for (int i = 0; i < 4; ++i) {
            const int idx = tid + i * 256;
            const int r = idx >> 4, c = idx & 15;
            As[r][c] = A[(long)(tm * 64 + r) * K + k0 + c];
            Ws[r][c] = (float)W[(long)(tn * 64 + r) * K + k0 + c];
        }
        __syncthreads();
#pragma unroll
        for (int kk = 0; kk < 16; ++kk) {
            float a[4], w[4];
#pragma unroll
            for (int r = 0; r < 4; ++r) a[r] = As[ty * 4 + r][kk];
#pragma unroll
            for (int c = 0; c < 4; ++c) w[c] = Ws[tx * 4 + c][kk];
#pragma unroll
            for (int r = 0; r < 4; ++r)
#pragma unroll
                for (int c = 0; c < 4; ++c) acc[r][c] += a[r] * w[c];
        }
    }
#pragma unroll
    for (int r = 0; r < 4; ++r)
#pragma unroll
        for (int c = 0; c < 4; ++c) {
            const int col = tn * 64 + tx * 4 + c;
            C[(long)(tm * 64 + ty * 4 + r) * N + col] = acc[r][c] * scales[col] + bias[col];
        }
}

extern "C" void kernel_launch(void* const* d_in, const int* in_sizes, int n_in,
                              void* d_out, int out_size, void* d_ws, size_t ws_size,
                              hipStream_t stream) {
    const float* A32    = (const float*)d_in[0];
    const int*   Wq     = (const int*)d_in[1];
    const float* scales = (const float*)d_in[2];
    const float* bias   = (const float*)d_in[3];
    float* C = (float*)d_out;

    const long aElems = in_sizes[0];        // M*K
    const long wElems = in_sizes[1];        // N*K
    const int  N = in_sizes[2];
    const int  K = (int)(wElems / N);
    const int  M = (int)(aElems / K);

    const size_t need = (size_t)aElems + (size_t)wElems + (size_t)M * 4 + 64;
    const bool ok = (M % 128 == 0) && (N % 256 == 0) && (K % 128 == 0) && (K >= 128) &&
                    ((long)M * K < 2000000000L) && ((long)N * K < 2000000000L);

    if (ws_size >= need && ok) {
        signed char* Aq  = (signed char*)d_ws;
        signed char* Wq8 = Aq + aElems;
        float* qrow = (float*)(Wq8 + wElems);
        quant_rows_kernel<<<M, 256, 0, stream>>>(A32, Aq, qrow, K);
        cvt_i32_i8_kernel<<<2048, 256, 0, stream>>>(Wq, Wq8, wElems);
        const int nwg = (M / 128) * (N / 256);
        gemm_i8_areg<<<nwg, 512, 32768, stream>>>(Aq, Wq8, qrow, scales, bias, C, M, N, K);
    } else {
        const int nwg = (M / 64) * (N / 64);
        gemm_fallback_kernel<<<nwg, 256, 0, stream>>>(A32, Wq, scales, bias, C, M, N, K);
    }
}

// Round 11
// 556.233 us; speedup vs baseline: 2.1751x; 2.1751x over previous
//
#include <hip/hip_runtime.h>
#include <hip/hip_bf16.h>
#include <stdint.h>

typedef float f32x4 __attribute__((ext_vector_type(4)));
typedef int i32x4 __attribute__((ext_vector_type(4)));

// ---------------- async global -> LDS (16B/lane, wave-uniform LDS base) ----------------
__device__ __forceinline__ void gload_lds16(const signed char* g, signed char* l) {
    __builtin_amdgcn_global_load_lds(
        (const __attribute__((address_space(1))) unsigned int*)g,
        (__attribute__((address_space(3))) unsigned int*)l,
        16, 0, 0);
}

// ---------------- per-row activation quantization: f32 -> i8, qrow = amax/127 ----------------
__global__ __launch_bounds__(256) void quant_rows_kernel(
        const float* __restrict__ A, signed char* __restrict__ Aq,
        float* __restrict__ qrow, int K) {
    const long row = blockIdx.x;
    const float* a = A + row * (long)K;
    signed char* o = Aq + row * (long)K;
    const int tid = threadIdx.x;
    const int nch = K >> 2;                       // f32x4 chunks per row
    float amax = 0.f;
    for (int c = tid; c < nch; c += 256) {
        f32x4 v = ((const f32x4*)a)[c];
        amax = fmaxf(amax, fmaxf(fmaxf(fabsf(v[0]), fabsf(v[1])),
                                 fmaxf(fabsf(v[2]), fabsf(v[3]))));
    }
#pragma unroll
    for (int off = 32; off; off >>= 1)
        amax = fmaxf(amax, __shfl_xor(amax, off, 64));
    __shared__ float red[4];
    if ((tid & 63) == 0) red[tid >> 6] = amax;
    __syncthreads();
    amax = fmaxf(fmaxf(red[0], red[1]), fmaxf(red[2], red[3]));
    const float s = amax > 0.f ? 127.f / amax : 0.f;
    if (tid == 0) qrow[row] = amax > 0.f ? amax / 127.f : 0.f;
    for (int c = tid; c < nch; c += 256) {       // second sweep: row is L1/L2-hot
        f32x4 v = ((const f32x4*)a)[c];
        int r = 0;
#pragma unroll
        for (int i = 0; i < 4; ++i) {
            int q = (int)__builtin_rintf(v[i] * s);
            r |= (q & 0xff) << (8 * i);
        }
        ((int*)o)[c] = r;
    }
}

// ---------------- weight conversion: i32 (int8-range) -> i8, exact ----------------
__global__ __launch_bounds__(256) void cvt_i32_i8_kernel(
        const int* __restrict__ in, signed char* __restrict__ out, long n) {
    long base = ((long)blockIdx.x * 256 + threadIdx.x) * 16;
    long stride = (long)gridDim.x * 256 * 16;
    for (long i = base; i < n; i += stride) {
        i32x4 pk;
#pragma unroll
        for (int c = 0; c < 4; ++c) {
            i32x4 v = *(const i32x4*)(in + i + c * 4);
            pk[c] = (v[0] & 0xff) | ((v[1] & 0xff) << 8) |
                    ((v[2] & 0xff) << 16) | ((v[3] & 0xff) << 24);
        }
        *(i32x4*)(out + i) = pk;
    }
}

// =====================================================================
// 128x256 i8 GEMM, BK=64, 4-wave block (1 wave/SIMD), 2 blocks/CU.
// Cross-block overlap: the co-resident block's MFMA cluster hides this
// block's LDS/sync phases (independent barriers).
// LDS 48 KiB/block: buf*24576 + {A:0 (8KB), B:8192 (16KB)}, 64-B rows,
// swizzle: LDS[row][slot16B] holds global k-chunk slot ^ ((row>>1)&3).
// Phase t: {STAGE(t+1) 6x gload_lds; vm(6)[stage t landed]; BAR;
//           12x ds_read(buf t); lgkm0; 32 MFMA; BAR}.
// Ledger: entering=6(stage t) -> +6 -> vm(6) drains stage t.  Last: vm(0).
// =====================================================================

#define BARw()  __builtin_amdgcn_s_barrier()
#define LG0()   { asm volatile("s_waitcnt lgkmcnt(0)" ::: "memory"); \
                  __builtin_amdgcn_sched_barrier(0); }
#define VM6()   asm volatile("s_waitcnt vmcnt(6)" ::: "memory")
#define VM0()   asm volatile("s_waitcnt vmcnt(0)" ::: "memory")

__global__ __launch_bounds__(256, 2) void gemm_i8_2blk(
        const signed char* __restrict__ A,      // [M][K] i8
        const signed char* __restrict__ W,      // [N][K] i8
        const float* __restrict__ qrow,         // [M] row dequant scale
        const float* __restrict__ scales,       // [N]
        const float* __restrict__ bias,         // [N]
        float* __restrict__ C,                  // [M][N]
        int M, int N, int K) {
    extern __shared__ signed char smem[];       // 49152 B

    const int tid  = threadIdx.x;
    const int lane = tid & 63;
    const int wid  = tid >> 6;                  // wave = N quarter (wc)
    const int wc   = wid;
    const int fr = lane & 15;
    const int kg = lane >> 4;

    const int nwg = gridDim.x;
    const int bid = blockIdx.x;
    const int swz = ((nwg & 7) == 0) ? ((bid & 7) * (nwg >> 3) + (bid >> 3)) : bid;
    const int tiles_m = M >> 7;                 // M / 128
    const int tn = swz / tiles_m;               // tn-major: consecutive share W panel
    const int tm = swz % tiles_m;
    const int arow = tm << 7;                   // tile M = 128
    const int brow = tn << 8;                   // tile N = 256

    // ---- stage offsets (thread-constant; bytes)
    const int srow = tid >> 2;                  // 0..63
    const int sswz = ((tid & 3) ^ ((srow >> 1) & 3)) << 4;   // pre-swizzled source col
    const int aOff0 = (arow + srow) * K + sswz;
    const int wOff0 = (brow + srow) * K + sswz;
    const int ldsSt = wid * 1024;
    const int K64 = K * 64;

    // ---- LDS read base (same formula for A and B rows: bits 1-2 of row = fr's)
    const int rdBase = fr * 64 + ((kg ^ ((fr >> 1) & 3)) << 4);

#define STAGE(T, BUF) {                                                       \
    const int koff = (T) * 64;                                                \
    gload_lds16(A + aOff0 + koff,            smem + (BUF)*24576 + ldsSt);     \
    gload_lds16(A + aOff0 + K64 + koff,      smem + (BUF)*24576 + 4096 + ldsSt); \
    gload_lds16(W + wOff0 + koff,            smem + (BUF)*24576 + 8192 + ldsSt); \
    gload_lds16(W + wOff0 + K64 + koff,      smem + (BUF)*24576 + 12288 + ldsSt); \
    gload_lds16(W + wOff0 + 2*K64 + koff,    smem + (BUF)*24576 + 16384 + ldsSt); \
    gload_lds16(W + wOff0 + 3*K64 + koff,    smem + (BUF)*24576 + 20480 + ldsSt); \
  }

    i32x4 acc[8][4] = {};
    i32x4 fa[8], fb[4];

    const int NT = K >> 6;       // K-tiles of 64; NT >= 2

    // ---- prologue: stage tile 0 into buf0
    STAGE(0, 0);

    // ---- main loop
    for (int t = 0; t < NT - 1; ++t) {
        STAGE(t + 1, (t + 1) & 1);
        VM6();                                  // own stage(t) issues landed
        BARw();                                 // all waves' stage(t) landed
        const signed char* rb = smem + (t & 1) * 24576;
#pragma unroll
        for (int ml = 0; ml < 8; ++ml)
            fa[ml] = *(const i32x4*)(rb + ml * 1024 + rdBase);
#pragma unroll
        for (int nl = 0; nl < 4; ++nl)
            fb[nl] = *(const i32x4*)(rb + 8192 + wc * 4096 + nl * 1024 + rdBase);
        LG0();
        __builtin_amdgcn_s_setprio(1);
#pragma unroll
        for (int ml = 0; ml < 8; ++ml)
#pragma unroll
            for (int nl = 0; nl < 4; ++nl)
                acc[ml][nl] = __builtin_amdgcn_mfma_i32_16x16x64_i8(
                    fa[ml], fb[nl], acc[ml][nl], 0, 0, 0);
        __builtin_amdgcn_s_setprio(0);
        BARw();                                 // reads done before next stage overwrites
    }

    // ---- last K-tile (no stage)
    VM0();
    BARw();
    {
        const signed char* rb = smem + ((NT - 1) & 1) * 24576;
#pragma unroll
        for (int ml = 0; ml < 8; ++ml)
            fa[ml] = *(const i32x4*)(rb + ml * 1024 + rdBase);
#pragma unroll
        for (int nl = 0; nl < 4; ++nl)
            fb[nl] = *(const i32x4*)(rb + 8192 + wc * 4096 + nl * 1024 + rdBase);
        LG0();
        __builtin_amdgcn_s_setprio(1);
#pragma unroll
        for (int ml = 0; ml < 8; ++ml)
#pragma unroll
            for (int nl = 0; nl < 4; ++nl)
                acc[ml][nl] = __builtin_amdgcn_mfma_i32_16x16x64_i8(
                    fa[ml], fb[nl], acc[ml][nl], 0, 0, 0);
        __builtin_amdgcn_s_setprio(0);
    }

#undef STAGE

    // ---- C write: out = acc * qrow[row] * scales[col] + bias[col]
    // 16x16 C/D layout: col = lane&15, row = (lane>>4)*4 + reg
#pragma unroll
    for (int nl = 0; nl < 4; ++nl) {
        const int col = brow + wc * 64 + nl * 16 + fr;
        const float s = scales[col];
        const float bb = bias[col];
#pragma unroll
        for (int ml = 0; ml < 8; ++ml) {
            const int row0 = arow + ml * 16 + kg * 4;
#pragma unroll
            for (int j = 0; j < 4; ++j)
                C[(long)(row0 + j) * N + col] =
                    (float)acc[ml][nl][j] * (qrow[row0 + j] * s) + bb;
        }
    }
}

// ---------------- fallback: plain fp32 (odd shapes / tiny ws only) ----------------
__global__ __launch_bounds__(256) void gemm_fallback_kernel(
        const float* __restrict__ A, const int* __restrict__ W,
        const float* __restrict__ scales, const float* __restrict__ bias,
        float* __restrict__ C, int M, int N, int K) {
    __shared__ float As[64][16];
    __shared__ float Ws[64][16];
    const int tiles_n = N / 64;
    const int tm = blockIdx.x / tiles_n, tn = blockIdx.x % tiles_n;
    const int tid = threadIdx.x, tx = tid & 15, ty = tid >> 4;
    float acc[4][4] = {};
    for (int k0 = 0; k0 < K; k0 += 16) {
        __syncthreads();
#pragma unroll
        for (int i = 0; i < 4; ++i) {
            const int idx = tid + i * 256;
            const int r = idx >> 4, c = idx & 15;
            As[r][c] = A[(long)(tm * 64 + r) * K + k0 + c];
            Ws[r][c] = (float)W[(long)(tn * 64 + r) * K + k0 + c];
        }
        __syncthreads();
#pragma unroll
        for (int kk = 0; kk < 16; ++kk) {
            float a[4], w[4];
#pragma unroll
            for (int r = 0; r < 4; ++r) a[r] = As[ty * 4 + r][kk];
#pragma unroll
            for (int c = 0; c < 4; ++c) w[c] = Ws[tx * 4 + c][kk];
#pragma unroll
            for (int r = 0; r < 4; ++r)
#pragma unroll
                for (int c = 0; c < 4; ++c) acc[r][c] += a[r] * w[c];
        }
    }
#pragma unroll
    for (int r = 0; r < 4; ++r)
#pragma unroll
        for (int c = 0; c < 4; ++c) {
            const int col = tn * 64 + tx * 4 + c;
            C[(long)(tm * 64 + ty * 4 + r) * N + col] = acc[r][c] * scales[col] + bias[col];
        }
}

extern "C" void kernel_launch(void* const* d_in, const int* in_sizes, int n_in,
                              void* d_out, int out_size, void* d_ws, size_t ws_size,
                              hipStream_t stream) {
    const float* A32    = (const float*)d_in[0];
    const int*   Wq     = (const int*)d_in[1];
    const float* scales = (const float*)d_in[2];
    const float* bias   = (const float*)d_in[3];
    float* C = (float*)d_out;

    const long aElems = in_sizes[0];        // M*K
    const long wElems = in_sizes[1];        // N*K
    const int  N = in_sizes[2];
    const int  K = (int)(wElems / N);
    const int  M = (int)(aElems / K);

    const size_t need = (size_t)aElems + (size_t)wElems + (size_t)M * 4 + 64;
    const bool ok = (M % 128 == 0) && (N % 256 == 0) && (K % 128 == 0) && (K >= 128) &&
                    ((long)M * K < 2000000000L) && ((long)N * K < 2000000000L);

    if (ws_size >= need && ok) {
        signed char* Aq  = (signed char*)d_ws;
        signed char* Wq8 = Aq + aElems;
        float* qrow = (float*)(Wq8 + wElems);
        quant_rows_kernel<<<M, 256, 0, stream>>>(A32, Aq, qrow, K);
        cvt_i32_i8_kernel<<<2048, 256, 0, stream>>>(Wq, Wq8, wElems);
        const int nwg = (M / 128) * (N / 256);
        gemm_i8_2blk<<<nwg, 256, 49152, stream>>>(Aq, Wq8, qrow, scales, bias, C, M, N, K);
    } else {
        const int nwg = (M / 64) * (N / 64);
        gemm_fallback_kernel<<<nwg, 256, 0, stream>>>(A32, Wq, scales, bias, C, M, N, K);
    }
}